// Round 4
// baseline (231.098 us; speedup 1.0000x reference)
//
#include <hip/hip_runtime.h>
#include <hip/hip_cooperative_groups.h>
#include <stdint.h>

namespace cg = cooperative_groups;

#define T_LEN 524288
#define SEG 8
#define WARM 8
#define EPC (SEG + WARM + 1)   // 17 staged (t,x) entries per chain
#define CHAINS 16
#define GSP (CHAINS * SEG)     // 128 spikes per wave-group
#define NBLK 512
#define NTHR 256
#define WPB 4                  // waves per block
#define NWAVE (NBLK * WPB)     // 2048 chain waves
#define CBLK 1536              // fallback chain grid

typedef short short8 __attribute__((ext_vector_type(8)));
typedef float f4 __attribute__((ext_vector_type(4)));
#define KEEPA(v) asm volatile("" : "+v"(v))

// ---- workspace layout (bytes) ----
static const size_t OFF_MASK = 0;                      // T uint8 (fallback only)
static const size_t OFF_CNT  = T_LEN;                  // 512 int
static const size_t OFF_N    = T_LEN + 4096;           // 1 int (fallback only)
static const size_t OFF_SPK  = T_LEN + 8192;           // T int

__device__ __forceinline__ short bfr(float f) {        // fp32 -> bf16 RNE
    uint32_t u = __float_as_uint(f);
    u = (u + 0x7fffu + ((u >> 16) & 1u)) >> 16;
    return (short)u;
}

// padded LDS index: +1 word per 32 -> lane-stride-4 accesses are 2 lanes/bank (free)
#define IDX(j) ((j) + ((j) >> 5))

// ================= fused cooperative kernel =================
struct SMP1 { float tile[1190]; float cs2[1190]; float wsum[4]; };
struct SMP2 { int wpre[4]; int wall[4]; int wtot[4]; };
struct SMP3 { float2 st[WPB][CHAINS * EPC]; unsigned hx[WPB][CHAINS * 20]; float ab[WPB][2 * GSP]; };
union SMU { SMP1 p1; SMP2 p2; SMP3 p3; };

__global__ __launch_bounds__(NTHR, 2)
void k_fused(const float* __restrict__ x,  const float* __restrict__ Wih,
             const float* __restrict__ Whh, const float* __restrict__ bih,
             const float* __restrict__ bhh, const float* __restrict__ Wv,
             const float* __restrict__ bv,  const float* __restrict__ Wsc,
             const float* __restrict__ bs,  float* __restrict__ out, int out_size,
             int* __restrict__ cnt, int* __restrict__ spk)
{
    __shared__ SMU sm;
    __shared__ int s_tot, s_base, s_N;
    cg::grid_group grid = cg::this_grid();

    const int tid = threadIdx.x;
    const int lane = tid & 63, w4 = tid >> 6;
    const int b = blockIdx.x;
    const int m = lane & 15, quad = lane >> 4;

    // ---- phase 1: spike mask via block-local prefix of x^2 ----
    if (tid == 0) s_tot = 0;
    const int mbs = b * 1024;
    for (int j = tid; j < 1154; j += NTHR) {
        int g = mbs - 130 + j;
        sm.p1.tile[IDX(j)] = (g >= 0) ? x[g] : 0.f;
    }
    __syncthreads();
    const int j0 = tid * 5;
    float p[5]; float run = 0.f;
    #pragma unroll
    for (int k = 0; k < 5; ++k) {
        float v = (j0 + k < 1154) ? sm.p1.tile[IDX(j0 + k)] : 0.f;
        run = fmaf(v, v, run);
        p[k] = run;
    }
    float incl = run;
    for (int d = 1; d < 64; d <<= 1) {
        float u = __shfl_up(incl, d, 64);
        if (lane >= d) incl += u;
    }
    if (lane == 63) sm.p1.wsum[w4] = incl;
    __syncthreads();
    float bbase = incl - run;
    for (int i = 0; i < w4; ++i) bbase += sm.p1.wsum[i];
    #pragma unroll
    for (int k = 0; k < 5; ++k)
        if (j0 + k < 1154) sm.p1.cs2[IDX(j0 + k)] = bbase + p[k];
    __syncthreads();

    const int loc = tid * 4;
    float tv[6];
    #pragma unroll
    for (int q = 0; q < 6; ++q) tv[q] = sm.p1.tile[IDX(loc + 128 + q)];
    uchar4 mv; float4 mf; int msum = 0;
    uint8_t* mp = &mv.x; float* fp = &mf.x;
    #pragma unroll
    for (int it = 0; it < 4; ++it) {
        int t = mbs + loc + it;
        int c = t < 128 ? (t < 1 ? 1 : t) : 128;
        float s = sm.p1.cs2[IDX(loc + 129 + it)] - sm.p1.cs2[IDX(loc + 1 + it)];
        float rms = sqrtf(fmaxf(s, 0.f) / (float)c) + 1e-8f;
        float xt = tv[it + 2];
        float pr = 2.f * tv[it + 1] - tv[it];
        bool mm = (t < 2) || (fabsf(xt - pr) > 2.5f * rms);
        mp[it] = mm ? 1 : 0; fp[it] = mm ? 1.f : 0.f; msum += mm ? 1 : 0;
    }
    int oi = T_LEN + 1 + mbs + loc;
    if (oi + 3 < out_size) *(float4*)(out + oi) = mf;
    int msum_r = msum;
    for (int d = 32; d; d >>= 1) msum_r += __shfl_down(msum_r, d, 64);
    if (lane == 0) atomicAdd(&s_tot, msum_r);
    __syncthreads();
    if (tid == 0) cnt[b] = s_tot;

    // ---- hoisted chain weights (latency hides under grid sync spin) ----
    short8 A1[6], A2[6], A3;
    #pragma unroll
    for (int t = 0; t < 6; ++t) {
        union { short s[8]; short8 v; } u1, u2;
        int rowg = 16 * t + m;
        #pragma unroll
        for (int j = 0; j < 8; ++j) {
            int k = 8 * quad + j;
            u1.s[j] = bfr(Whh[rowg * 32 + k]);
            float a2v = 0.f;
            if (k == 0) a2v = Wih[rowg * 2];
            else if (k == 1) a2v = Wih[rowg * 2 + 1];
            else if (k == 2) a2v = (rowg < 64) ? (bih[rowg] + bhh[rowg]) : bih[rowg];
            u2.s[j] = bfr(a2v);
        }
        A1[t] = u1.v; A2[t] = u2.v;
    }
    {
        union { short s[8]; short8 v; } u3;
        #pragma unroll
        for (int j = 0; j < 8; ++j) {
            int k = 8 * quad + j;
            float v = (m == 0) ? Wv[k] : (m == 1) ? Wsc[k] : 0.f;
            u3.s[j] = bfr(v);
        }
        A3 = u3.v;
    }
    #pragma unroll
    for (int t = 0; t < 6; ++t) { KEEPA(A1[t]); KEEPA(A2[t]); }
    KEEPA(A3);
    float bn0[4], bn1[4];
    #pragma unroll
    for (int e = 0; e < 4; ++e) {
        int r0 = quad * 4 + e;
        bn0[e] = bhh[64 + r0];  bn1[e] = bhh[80 + r0];
    }
    const float bv0 = bv[0], bs0 = bs[0];

    grid.sync();

    // ---- phase 2: global prefix of cnt + scatter (mask kept in registers) ----
    {
        int v1 = cnt[tid];
        int v2 = cnt[tid + 256];
        int pre = ((tid < b) ? v1 : 0) + ((tid + 256 < b) ? v2 : 0);
        int allv = v1 + v2;
        for (int d = 32; d; d >>= 1) {
            pre  += __shfl_down(pre,  d, 64);
            allv += __shfl_down(allv, d, 64);
        }
        if (lane == 0) { sm.p2.wpre[w4] = pre; sm.p2.wall[w4] = allv; }
        __syncthreads();
        if (tid == 0) {
            int sb = sm.p2.wpre[0] + sm.p2.wpre[1] + sm.p2.wpre[2] + sm.p2.wpre[3];
            int sn = sm.p2.wall[0] + sm.p2.wall[1] + sm.p2.wall[2] + sm.p2.wall[3];
            s_base = sb; s_N = sn;
            if (b == NBLK - 1 && T_LEN < out_size) out[T_LEN] = (float)sn;
        }
        int m0 = mv.x, m1 = mv.y, m2 = mv.z, m3 = mv.w;
        int e1 = m0, e2 = m0 + m1, e3 = m0 + m1 + m2, tsum = e3 + m3;
        int incs = tsum;
        for (int d = 1; d < 64; d <<= 1) {
            int u = __shfl_up(incs, d, 64);
            if (lane >= d) incs += u;
        }
        if (lane == 63) sm.p2.wtot[w4] = incs;
        __syncthreads();                 // publishes wtot AND s_base/s_N
        int woff = 0;
        for (int i = 0; i < w4; i++) woff += sm.p2.wtot[i];
        int texcl = woff + incs - tsum;
        int g = s_base + texcl;
        int ee[4] = {0, e1, e2, e3};
        int mm4[4] = {m0, m1, m2, m3};
        #pragma unroll
        for (int k = 0; k < 4; k++) {
            if (mm4[k]) spk[g + ee[k]] = mbs + loc + k;
        }
    }

    grid.sync();

    // ---- phase 3: MFMA-batched GRU chains, one spike-group per wave ----
    const int N = s_N;
    float2*   st = sm.p3.st[w4];
    unsigned* hx = sm.p3.hx[w4];
    float*    ab = sm.p3.ab[w4];
    const int wid = b * WPB + w4;

    for (int g0 = wid; g0 * GSP < N; g0 += NWAVE) {
        const int base0 = g0 * GSP;
        for (int e = lane; e < CHAINS * EPC; e += 64) {
            int n = e / EPC, j = e - n * EPC;
            int s = base0 + n * SEG - (WARM + 1) + j;
            s = min(max(s, 0), N - 1);
            int t = spk[s];
            st[e] = make_float2((float)t, x[t]);
        }
        __builtin_amdgcn_wave_barrier();

        float h0[4], h1[4];
        #pragma unroll
        for (int e = 0; e < 4; ++e) { h0[e] = 0.f; h1[e] = 0.f; }
        short8 B1 = (short8)0;
        float tprev = st[m * EPC].x;

        for (int j = 0; j < SEG + WARM; ++j) {
            float2 cur = st[m * EPC + j + 1];   // 4 lanes/chain same addr: broadcast
            float xt = cur.y;
            float d = (cur.x - tprev) * 0.0078125f;
            tprev = cur.x;

            unsigned p0 = (__float_as_uint(d) & 0xFFFF0000u) | (__float_as_uint(xt) >> 16);
            unsigned p1 = 0x00003F80u;
            p0 = (quad == 0) ? p0 : 0u;
            p1 = (quad == 0) ? p1 : 0u;
            union { unsigned u[4]; short8 v; } b2u;
            b2u.u[0] = p0; b2u.u[1] = p1; b2u.u[2] = 0u; b2u.u[3] = 0u;
            short8 B2 = b2u.v;

            f4 z4 = {0.f, 0.f, 0.f, 0.f};
            f4 Drz[4], Dh0, Dh1, Di0, Di1;
            f4 tmp0 = __builtin_amdgcn_mfma_f32_16x16x32_bf16(A2[0], B2, z4, 0, 0, 0);
            f4 tmp1 = __builtin_amdgcn_mfma_f32_16x16x32_bf16(A2[1], B2, z4, 0, 0, 0);
            f4 tmp2 = __builtin_amdgcn_mfma_f32_16x16x32_bf16(A2[2], B2, z4, 0, 0, 0);
            f4 tmp3 = __builtin_amdgcn_mfma_f32_16x16x32_bf16(A2[3], B2, z4, 0, 0, 0);
            Di0 = __builtin_amdgcn_mfma_f32_16x16x32_bf16(A2[4], B2, z4, 0, 0, 0);
            Di1 = __builtin_amdgcn_mfma_f32_16x16x32_bf16(A2[5], B2, z4, 0, 0, 0);
            Drz[0] = __builtin_amdgcn_mfma_f32_16x16x32_bf16(A1[0], B1, tmp0, 0, 0, 0);
            Drz[1] = __builtin_amdgcn_mfma_f32_16x16x32_bf16(A1[1], B1, tmp1, 0, 0, 0);
            Drz[2] = __builtin_amdgcn_mfma_f32_16x16x32_bf16(A1[2], B1, tmp2, 0, 0, 0);
            Drz[3] = __builtin_amdgcn_mfma_f32_16x16x32_bf16(A1[3], B1, tmp3, 0, 0, 0);
            Dh0 = __builtin_amdgcn_mfma_f32_16x16x32_bf16(A1[4], B1, z4, 0, 0, 0);
            Dh1 = __builtin_amdgcn_mfma_f32_16x16x32_bf16(A1[5], B1, z4, 0, 0, 0);

            #pragma unroll
            for (int e = 0; e < 4; ++e) {
                float r0 = __builtin_amdgcn_rcpf(1.f + __builtin_amdgcn_exp2f(-1.44269504089f * Drz[0][e]));
                float r1 = __builtin_amdgcn_rcpf(1.f + __builtin_amdgcn_exp2f(-1.44269504089f * Drz[1][e]));
                float zz0 = __builtin_amdgcn_rcpf(1.f + __builtin_amdgcn_exp2f(-1.44269504089f * Drz[2][e]));
                float zz1 = __builtin_amdgcn_rcpf(1.f + __builtin_amdgcn_exp2f(-1.44269504089f * Drz[3][e]));
                float np0 = fmaf(r0, Dh0[e] + bn0[e], Di0[e]);
                float np1 = fmaf(r1, Dh1[e] + bn1[e], Di1[e]);
                float en0 = __builtin_amdgcn_exp2f(2.88539008178f * np0);
                float en1 = __builtin_amdgcn_exp2f(2.88539008178f * np1);
                float n0 = fmaf(-2.f, __builtin_amdgcn_rcpf(1.f + en0), 1.f);
                float n1 = fmaf(-2.f, __builtin_amdgcn_rcpf(1.f + en1), 1.f);
                h0[e] = fmaf(zz0, h0[e] - n0, n0);
                h1[e] = fmaf(zz1, h1[e] - n1, n1);
            }

            unsigned q0 = (__float_as_uint(h0[1]) & 0xFFFF0000u) | (__float_as_uint(h0[0]) >> 16);
            unsigned q1 = (__float_as_uint(h0[3]) & 0xFFFF0000u) | (__float_as_uint(h0[2]) >> 16);
            unsigned q2 = (__float_as_uint(h1[1]) & 0xFFFF0000u) | (__float_as_uint(h1[0]) >> 16);
            unsigned q3 = (__float_as_uint(h1[3]) & 0xFFFF0000u) | (__float_as_uint(h1[2]) >> 16);
            *(uint2*)&hx[m * 20 + 2 * quad]     = make_uint2(q0, q1);
            *(uint2*)&hx[m * 20 + 8 + 2 * quad] = make_uint2(q2, q3);
            __builtin_amdgcn_wave_barrier();
            union { uint4 u; short8 v; } bu;
            bu.u = *(const uint4*)&hx[m * 20 + 4 * quad];
            B1 = bu.v;

            if (j >= WARM) {
                f4 Dab = __builtin_amdgcn_mfma_f32_16x16x32_bf16(A3, B1, z4, 0, 0, 0);
                if (quad == 0) {
                    int sg = base0 + m * SEG + (j - WARM);
                    if (sg < N)
                        *(float2*)&ab[2 * (m * SEG + j - WARM)] =
                            make_float2(Dab[0] + bv0, Dab[1] + bs0);
                }
            }
        }
        __builtin_amdgcn_wave_barrier();

        const int nid = base0 + GSP;
        const int tN = (nid >= N) ? T_LEN : spk[nid];
        #pragma unroll
        for (int h = 0; h < 2; ++h) {
            int sl = lane + 64 * h;
            int sg = base0 + sl;
            if (sg < N) {
                int n = sl >> 3, jj = sl & 7;
                float ts = st[n * EPC + (WARM + 1) + jj].x;
                int tnext;
                if (sg + 1 >= N) tnext = T_LEN;
                else if (sl + 1 < GSP) {
                    int n2 = (sl + 1) >> 3, j2 = (sl + 1) & 7;
                    tnext = (int)st[n2 * EPC + (WARM + 1) + j2].x;
                } else tnext = tN;
                float2 abv = *(const float2*)&ab[2 * sl];
                int tsi = (int)ts;
                for (int t = tsi; t < tnext; ++t)
                    out[t] = fmaf(abv.y, (float)(t - tsi) * 0.0078125f, abv.x);
            }
        }
        __builtin_amdgcn_wave_barrier();
    }
}

// ================= fallback path (proven 3-kernel pipeline) =================
__global__ __launch_bounds__(256) void k_mask(const float* __restrict__ x,
                                              uint8_t* __restrict__ mask,
                                              float* __restrict__ out, int out_size,
                                              int* __restrict__ cnt)
{
    __shared__ float tile[1190];
    __shared__ float cs2[1190];
    __shared__ float wsum[4];
    __shared__ int tot;
    const int bs = blockIdx.x * 1024;
    const int tid = threadIdx.x;
    const int lane = tid & 63, w = tid >> 6;
    if (tid == 0) tot = 0;
    for (int j = tid; j < 1154; j += 256) {
        int g = bs - 130 + j;
        tile[IDX(j)] = (g >= 0) ? x[g] : 0.f;
    }
    __syncthreads();
    const int j0 = tid * 5;
    float p[5];
    float run = 0.f;
    #pragma unroll
    for (int k = 0; k < 5; ++k) {
        float v = (j0 + k < 1154) ? tile[IDX(j0 + k)] : 0.f;
        run = fmaf(v, v, run);
        p[k] = run;
    }
    float incl = run;
    for (int d = 1; d < 64; d <<= 1) {
        float u = __shfl_up(incl, d, 64);
        if (lane >= d) incl += u;
    }
    if (lane == 63) wsum[w] = incl;
    __syncthreads();
    float base = incl - run;
    for (int i = 0; i < w; ++i) base += wsum[i];
    #pragma unroll
    for (int k = 0; k < 5; ++k)
        if (j0 + k < 1154) cs2[IDX(j0 + k)] = base + p[k];
    __syncthreads();

    const int loc = tid * 4;
    float tv[6];
    #pragma unroll
    for (int q = 0; q < 6; ++q) tv[q] = tile[IDX(loc + 128 + q)];
    uchar4 mv; float4 mf; int msum = 0;
    uint8_t* mp = &mv.x; float* fp = &mf.x;
    #pragma unroll
    for (int it = 0; it < 4; ++it) {
        int t = bs + loc + it;
        int c = t < 128 ? (t < 1 ? 1 : t) : 128;
        float s = cs2[IDX(loc + 129 + it)] - cs2[IDX(loc + 1 + it)];
        float rms = sqrtf(fmaxf(s, 0.f) / (float)c) + 1e-8f;
        float xt = tv[it + 2];
        float pr = 2.f * tv[it + 1] - tv[it];
        bool m = (t < 2) || (fabsf(xt - pr) > 2.5f * rms);
        mp[it] = m ? 1 : 0; fp[it] = m ? 1.f : 0.f; msum += m ? 1 : 0;
    }
    *(uchar4*)(mask + bs + loc) = mv;
    int oi = T_LEN + 1 + bs + loc;
    if (oi + 3 < out_size) *(float4*)(out + oi) = mf;
    for (int d = 32; d; d >>= 1) msum += __shfl_down(msum, d, 64);
    if ((tid & 63) == 0) atomicAdd(&tot, msum);
    __syncthreads();
    if (tid == 0) cnt[blockIdx.x] = tot;
}

__global__ __launch_bounds__(256) void k_scatter(const uint8_t* __restrict__ mask,
                                                 const int* __restrict__ cnt,
                                                 int* __restrict__ spk,
                                                 int* __restrict__ nspk,
                                                 float* __restrict__ out, int out_size)
{
    __shared__ int wtot[4];
    __shared__ int wpre[4];
    __shared__ int s_base;
    const int tid = threadIdx.x, b = blockIdx.x;
    int pre = 0;
    #pragma unroll
    for (int i = tid; i < 512; i += 256)
        pre += (i < b) ? cnt[i] : 0;
    for (int d = 32; d; d >>= 1) pre += __shfl_down(pre, d, 64);
    if ((tid & 63) == 0) wpre[tid >> 6] = pre;
    __syncthreads();
    if (tid == 0) {
        int t0 = wpre[0] + wpre[1] + wpre[2] + wpre[3];
        s_base = t0;
        if (b == 511) {
            int total = t0 + cnt[511];
            *nspk = total;
            if (T_LEN < out_size) out[T_LEN] = (float)total;
        }
    }
    const int base = b * 1024 + tid * 4;
    uchar4 mv = *(const uchar4*)(mask + base);
    int m0 = mv.x, m1 = mv.y, m2 = mv.z, m3 = mv.w;
    int e1 = m0, e2 = m0 + m1, e3 = m0 + m1 + m2, tsum = e3 + m3;
    int lane = tid & 63, w = tid >> 6;
    int incl = tsum;
    for (int d = 1; d < 64; d <<= 1) {
        int u = __shfl_up(incl, d, 64);
        if (lane >= d) incl += u;
    }
    if (lane == 63) wtot[w] = incl;
    __syncthreads();
    int woff = 0;
    for (int i = 0; i < w; i++) woff += wtot[i];
    int texcl = woff + incl - tsum;
    int g = s_base + texcl;
    int e[4] = {0, e1, e2, e3};
    int m[4] = {m0, m1, m2, m3};
    #pragma unroll
    for (int k = 0; k < 4; k++) {
        if (m[k]) spk[g + e[k]] = base + k;
    }
}

__global__ __attribute__((amdgpu_waves_per_eu(2)))
__launch_bounds__(64)
void k_chain(const float* __restrict__ Whh,
             const float* __restrict__ Wih,
             const float* __restrict__ bih,
             const float* __restrict__ bhh,
             const int* __restrict__ spk,
             const float* __restrict__ x,
             const int* __restrict__ nspk,
             const float* __restrict__ Wv,
             const float* __restrict__ bv,
             const float* __restrict__ Wsc,
             const float* __restrict__ bs,
             float* __restrict__ out)
{
    __shared__ float2   st[CHAINS * EPC];
    __shared__ unsigned hx[CHAINS * 20];
    __shared__ float    ab[2 * GSP];

    const int lane = threadIdx.x;
    const int m = lane & 15;
    const int quad = lane >> 4;
    const int N = *nspk;

    short8 A1[6], A2[6], A3;
    #pragma unroll
    for (int t = 0; t < 6; ++t) {
        union { short s[8]; short8 v; } u1, u2;
        int rowg = 16 * t + m;
        #pragma unroll
        for (int j = 0; j < 8; ++j) {
            int k = 8 * quad + j;
            u1.s[j] = bfr(Whh[rowg * 32 + k]);
            float a2v = 0.f;
            if (k == 0) a2v = Wih[rowg * 2];
            else if (k == 1) a2v = Wih[rowg * 2 + 1];
            else if (k == 2) a2v = (rowg < 64) ? (bih[rowg] + bhh[rowg]) : bih[rowg];
            u2.s[j] = bfr(a2v);
        }
        A1[t] = u1.v; A2[t] = u2.v;
    }
    {
        union { short s[8]; short8 v; } u3;
        #pragma unroll
        for (int j = 0; j < 8; ++j) {
            int k = 8 * quad + j;
            float v = (m == 0) ? Wv[k] : (m == 1) ? Wsc[k] : 0.f;
            u3.s[j] = bfr(v);
        }
        A3 = u3.v;
    }
    #pragma unroll
    for (int t = 0; t < 6; ++t) { KEEPA(A1[t]); KEEPA(A2[t]); }
    KEEPA(A3);

    float bn0[4], bn1[4];
    #pragma unroll
    for (int e = 0; e < 4; ++e) {
        int r0 = quad * 4 + e;
        bn0[e] = bhh[64 + r0];  bn1[e] = bhh[80 + r0];
    }
    const float bv0 = bv[0], bs0 = bs[0];

    for (int g0 = blockIdx.x; g0 * GSP < N; g0 += CBLK) {
        const int base0 = g0 * GSP;
        for (int e = lane; e < CHAINS * EPC; e += 64) {
            int n = e / EPC, j = e - n * EPC;
            int s = base0 + n * SEG - (WARM + 1) + j;
            s = min(max(s, 0), N - 1);
            int t = spk[s];
            st[e] = make_float2((float)t, x[t]);
        }
        __builtin_amdgcn_wave_barrier();

        float h0[4], h1[4];
        #pragma unroll
        for (int e = 0; e < 4; ++e) { h0[e] = 0.f; h1[e] = 0.f; }
        short8 B1 = (short8)0;
        float tprev = st[m * EPC].x;

        for (int j = 0; j < SEG + WARM; ++j) {
            float2 cur = st[m * EPC + j + 1];
            float xt = cur.y;
            float d = (cur.x - tprev) * 0.0078125f;
            tprev = cur.x;

            unsigned p0 = (__float_as_uint(d) & 0xFFFF0000u) | (__float_as_uint(xt) >> 16);
            unsigned p1 = 0x00003F80u;
            p0 = (quad == 0) ? p0 : 0u;
            p1 = (quad == 0) ? p1 : 0u;
            union { unsigned u[4]; short8 v; } b2u;
            b2u.u[0] = p0; b2u.u[1] = p1; b2u.u[2] = 0u; b2u.u[3] = 0u;
            short8 B2 = b2u.v;

            f4 z4 = {0.f, 0.f, 0.f, 0.f};
            f4 Drz[4], Dh0, Dh1, Di0, Di1;
            f4 tmp0 = __builtin_amdgcn_mfma_f32_16x16x32_bf16(A2[0], B2, z4, 0, 0, 0);
            f4 tmp1 = __builtin_amdgcn_mfma_f32_16x16x32_bf16(A2[1], B2, z4, 0, 0, 0);
            f4 tmp2 = __builtin_amdgcn_mfma_f32_16x16x32_bf16(A2[2], B2, z4, 0, 0, 0);
            f4 tmp3 = __builtin_amdgcn_mfma_f32_16x16x32_bf16(A2[3], B2, z4, 0, 0, 0);
            Di0 = __builtin_amdgcn_mfma_f32_16x16x32_bf16(A2[4], B2, z4, 0, 0, 0);
            Di1 = __builtin_amdgcn_mfma_f32_16x16x32_bf16(A2[5], B2, z4, 0, 0, 0);
            Drz[0] = __builtin_amdgcn_mfma_f32_16x16x32_bf16(A1[0], B1, tmp0, 0, 0, 0);
            Drz[1] = __builtin_amdgcn_mfma_f32_16x16x32_bf16(A1[1], B1, tmp1, 0, 0, 0);
            Drz[2] = __builtin_amdgcn_mfma_f32_16x16x32_bf16(A1[2], B1, tmp2, 0, 0, 0);
            Drz[3] = __builtin_amdgcn_mfma_f32_16x16x32_bf16(A1[3], B1, tmp3, 0, 0, 0);
            Dh0 = __builtin_amdgcn_mfma_f32_16x16x32_bf16(A1[4], B1, z4, 0, 0, 0);
            Dh1 = __builtin_amdgcn_mfma_f32_16x16x32_bf16(A1[5], B1, z4, 0, 0, 0);

            #pragma unroll
            for (int e = 0; e < 4; ++e) {
                float r0 = __builtin_amdgcn_rcpf(1.f + __builtin_amdgcn_exp2f(-1.44269504089f * Drz[0][e]));
                float r1 = __builtin_amdgcn_rcpf(1.f + __builtin_amdgcn_exp2f(-1.44269504089f * Drz[1][e]));
                float zz0 = __builtin_amdgcn_rcpf(1.f + __builtin_amdgcn_exp2f(-1.44269504089f * Drz[2][e]));
                float zz1 = __builtin_amdgcn_rcpf(1.f + __builtin_amdgcn_exp2f(-1.44269504089f * Drz[3][e]));
                float np0 = fmaf(r0, Dh0[e] + bn0[e], Di0[e]);
                float np1 = fmaf(r1, Dh1[e] + bn1[e], Di1[e]);
                float en0 = __builtin_amdgcn_exp2f(2.88539008178f * np0);
                float en1 = __builtin_amdgcn_exp2f(2.88539008178f * np1);
                float n0 = fmaf(-2.f, __builtin_amdgcn_rcpf(1.f + en0), 1.f);
                float n1 = fmaf(-2.f, __builtin_amdgcn_rcpf(1.f + en1), 1.f);
                h0[e] = fmaf(zz0, h0[e] - n0, n0);
                h1[e] = fmaf(zz1, h1[e] - n1, n1);
            }

            unsigned q0 = (__float_as_uint(h0[1]) & 0xFFFF0000u) | (__float_as_uint(h0[0]) >> 16);
            unsigned q1 = (__float_as_uint(h0[3]) & 0xFFFF0000u) | (__float_as_uint(h0[2]) >> 16);
            unsigned q2 = (__float_as_uint(h1[1]) & 0xFFFF0000u) | (__float_as_uint(h1[0]) >> 16);
            unsigned q3 = (__float_as_uint(h1[3]) & 0xFFFF0000u) | (__float_as_uint(h1[2]) >> 16);
            *(uint2*)&hx[m * 20 + 2 * quad]     = make_uint2(q0, q1);
            *(uint2*)&hx[m * 20 + 8 + 2 * quad] = make_uint2(q2, q3);
            __builtin_amdgcn_wave_barrier();
            union { uint4 u; short8 v; } bu;
            bu.u = *(const uint4*)&hx[m * 20 + 4 * quad];
            B1 = bu.v;

            if (j >= WARM) {
                f4 Dab = __builtin_amdgcn_mfma_f32_16x16x32_bf16(A3, B1, z4, 0, 0, 0);
                if (quad == 0) {
                    int sg = base0 + m * SEG + (j - WARM);
                    if (sg < N)
                        *(float2*)&ab[2 * (m * SEG + j - WARM)] =
                            make_float2(Dab[0] + bv0, Dab[1] + bs0);
                }
            }
        }
        __builtin_amdgcn_wave_barrier();

        const int nid = base0 + GSP;
        const int tN = (nid >= N) ? T_LEN : spk[nid];
        #pragma unroll
        for (int h = 0; h < 2; ++h) {
            int sl = lane + 64 * h;
            int sg = base0 + sl;
            if (sg < N) {
                int n = sl >> 3, jj = sl & 7;
                float ts = st[n * EPC + (WARM + 1) + jj].x;
                int tnext;
                if (sg + 1 >= N) tnext = T_LEN;
                else if (sl + 1 < GSP) {
                    int n2 = (sl + 1) >> 3, j2 = (sl + 1) & 7;
                    tnext = (int)st[n2 * EPC + (WARM + 1) + j2].x;
                } else tnext = tN;
                float2 abv = *(const float2*)&ab[2 * sl];
                int tsi = (int)ts;
                for (int t = tsi; t < tnext; ++t)
                    out[t] = fmaf(abv.y, (float)(t - tsi) * 0.0078125f, abv.x);
            }
        }
        __builtin_amdgcn_wave_barrier();
    }
}

extern "C" void kernel_launch(void* const* d_in, const int* in_sizes, int n_in,
                              void* d_out, int out_size, void* d_ws, size_t ws_size,
                              hipStream_t stream)
{
    const float* x   = (const float*)d_in[0];
    const float* Wih = (const float*)d_in[1];
    const float* Whh = (const float*)d_in[2];
    const float* bih = (const float*)d_in[3];
    const float* bhh = (const float*)d_in[4];
    const float* Wv  = (const float*)d_in[5];
    const float* bv  = (const float*)d_in[6];
    const float* Wsc = (const float*)d_in[7];
    const float* bs  = (const float*)d_in[8];
    float* out = (float*)d_out;

    char* ws = (char*)d_ws;
    uint8_t* mask = (uint8_t*)(ws + OFF_MASK);
    int* cnt  = (int*)(ws + OFF_CNT);
    int* nspk = (int*)(ws + OFF_N);
    int* spk  = (int*)(ws + OFF_SPK);

    void* ka[13];
    ka[0]  = (void*)&x;   ka[1]  = (void*)&Wih; ka[2]  = (void*)&Whh;
    ka[3]  = (void*)&bih; ka[4]  = (void*)&bhh; ka[5]  = (void*)&Wv;
    ka[6]  = (void*)&bv;  ka[7]  = (void*)&Wsc; ka[8]  = (void*)&bs;
    ka[9]  = (void*)&out; ka[10] = (void*)&out_size;
    ka[11] = (void*)&cnt; ka[12] = (void*)&spk;

    hipError_t err = hipLaunchCooperativeKernel((const void*)k_fused,
                                                dim3(NBLK), dim3(NTHR),
                                                ka, 0, stream);
    if (err != hipSuccess) {
        // proven 3-kernel fallback
        k_mask<<<512, 256, 0, stream>>>(x, mask, out, out_size, cnt);
        k_scatter<<<512, 256, 0, stream>>>(mask, cnt, spk, nspk, out, out_size);
        k_chain<<<CBLK, 64, 0, stream>>>(Whh, Wih, bih, bhh, spk, x, nspk,
                                         Wv, bv, Wsc, bs, out);
    }
}

// Round 6
// 108.786 us; speedup vs baseline: 2.1243x; 2.1243x over previous
//
#include <hip/hip_runtime.h>
#include <stdint.h>

#define T_LEN 524288
#define SEG 8
#define WARM 8
#define EPC (SEG + WARM + 1)   // 17 staged (t,x) entries per chain
#define CHAINS 16
#define GSP (CHAINS * SEG)     // 128 spikes per wave-group
#define CBLK 1536              // chain blocks (1 wave each), grid-stride
#define NCH 512                // mask chunks (1024 t each)

typedef short short8 __attribute__((ext_vector_type(8)));
typedef float f4 __attribute__((ext_vector_type(4)));
#define KEEPA(v) asm volatile("" : "+v"(v))

// ---- workspace layout (bytes) ----
static const size_t OFF_MASK = 0;                      // T uint8
static const size_t OFF_CNT  = T_LEN;                  // 512 int

__device__ __forceinline__ short bfr(float f) {        // fp32 -> bf16 RNE
    uint32_t u = __float_as_uint(f);
    u = (u + 0x7fffu + ((u >> 16) & 1u)) >> 16;
    return (short)u;
}

// padded LDS index: +1 word per 32 -> lane-stride-4 accesses are 2 lanes/bank (free)
#define IDX(j) ((j) + ((j) >> 5))

// ---- K1: spike mask via block-local prefix sum of x^2 + per-1024-block count ----
__global__ __launch_bounds__(256) void k_mask(const float* __restrict__ x,
                                              uint8_t* __restrict__ mask,
                                              float* __restrict__ out, int out_size,
                                              int* __restrict__ cnt)
{
    __shared__ float tile[1190];                        // 1154 + pad
    __shared__ float cs2[1190];                         // inclusive prefix of squares
    __shared__ float wsum[4];
    __shared__ int tot;
    const int bs = blockIdx.x * 1024;
    const int tid = threadIdx.x;
    const int lane = tid & 63, w = tid >> 6;
    if (tid == 0) tot = 0;
    for (int j = tid; j < 1154; j += 256) {
        int g = bs - 130 + j;
        tile[IDX(j)] = (g >= 0) ? x[g] : 0.f;
    }
    __syncthreads();

    const int j0 = tid * 5;
    float p[5];
    float run = 0.f;
    #pragma unroll
    for (int k = 0; k < 5; ++k) {
        float v = (j0 + k < 1154) ? tile[IDX(j0 + k)] : 0.f;
        run = fmaf(v, v, run);
        p[k] = run;
    }
    float incl = run;
    for (int d = 1; d < 64; d <<= 1) {
        float u = __shfl_up(incl, d, 64);
        if (lane >= d) incl += u;
    }
    if (lane == 63) wsum[w] = incl;
    __syncthreads();
    float base = incl - run;            // exclusive within wave
    for (int i = 0; i < w; ++i) base += wsum[i];
    #pragma unroll
    for (int k = 0; k < 5; ++k)
        if (j0 + k < 1154) cs2[IDX(j0 + k)] = base + p[k];
    __syncthreads();

    const int loc = tid * 4;
    float tv[6];
    #pragma unroll
    for (int q = 0; q < 6; ++q) tv[q] = tile[IDX(loc + 128 + q)];
    uchar4 mv; float4 mf; int msum = 0;
    uint8_t* mp = &mv.x; float* fp = &mf.x;
    #pragma unroll
    for (int it = 0; it < 4; ++it) {
        int t = bs + loc + it;
        int c = t < 128 ? (t < 1 ? 1 : t) : 128;
        float s = cs2[IDX(loc + 129 + it)] - cs2[IDX(loc + 1 + it)];
        float rms = sqrtf(fmaxf(s, 0.f) / (float)c) + 1e-8f;
        float xt = tv[it + 2];
        float pr = 2.f * tv[it + 1] - tv[it];
        bool m = (t < 2) || (fabsf(xt - pr) > 2.5f * rms);
        mp[it] = m ? 1 : 0; fp[it] = m ? 1.f : 0.f; msum += m ? 1 : 0;
    }
    *(uchar4*)(mask + bs + loc) = mv;
    int oi = T_LEN + 1 + bs + loc;
    if (oi + 3 < out_size) *(float4*)(out + oi) = mf;
    for (int d = 32; d; d >>= 1) msum += __shfl_down(msum, d, 64);
    if ((tid & 63) == 0) atomicAdd(&tot, msum);
    __syncthreads();
    if (tid == 0) cnt[blockIdx.x] = tot;
}

// ---- K2: MFMA-batched GRU chains with in-kernel scatter (k_scatter deleted).
//      Each block: prefix cnt[512] -> P[], decode its own mask chunks, stage st[],
//      then the HW-verified chain body (identical to R10-verified code). ----
__global__ __attribute__((amdgpu_waves_per_eu(2)))
__launch_bounds__(64)
void k_chain(const float* __restrict__ Whh,
             const float* __restrict__ Wih,
             const float* __restrict__ bih,
             const float* __restrict__ bhh,
             const uint8_t* __restrict__ mask,
             const int* __restrict__ cnt,
             const float* __restrict__ x,
             const float* __restrict__ Wv,
             const float* __restrict__ bv,
             const float* __restrict__ Wsc,
             const float* __restrict__ bs,
             float* __restrict__ out, int out_size)
{
    __shared__ float2   st[CHAINS * EPC];   // staged (t, x_t)
    __shared__ unsigned hx[CHAINS * 20];    // packed bf16 h (C->B transpose)
    __shared__ float    ab[2 * GSP];        // (a,b) per spike
    __shared__ int      P[NCH + 1];         // exclusive prefix of chunk counts
    __shared__ int      tn_sh;              // time of spike base0+GSP (or T_LEN)

    const int lane = threadIdx.x;
    const int m = lane & 15;
    const int quad = lane >> 4;

    // ---- prologue: prefix of the 512 chunk counts (one wave, 8 values/lane) ----
    int vv[8]; int locs = 0;
    #pragma unroll
    for (int k = 0; k < 8; ++k) { vv[k] = cnt[lane * 8 + k]; locs += vv[k]; }
    int incp = locs;
    for (int d = 1; d < 64; d <<= 1) {
        int u = __shfl_up(incp, d, 64);
        if (lane >= d) incp += u;
    }
    int runp = incp - locs;
    #pragma unroll
    for (int k = 0; k < 8; ++k) { P[lane * 8 + k] = runp; runp += vv[k]; }
    if (lane == 63) P[NCH] = incp;
    __builtin_amdgcn_wave_barrier();
    const int N = P[NCH];
    if (blockIdx.x == 0 && lane == 0 && T_LEN < out_size) out[T_LEN] = (float)N;

    // ---- A fragments (static): A[m][k], k = 8*quad + j ----
    short8 A1[6], A2[6], A3;
    #pragma unroll
    for (int t = 0; t < 6; ++t) {
        union { short s[8]; short8 v; } u1, u2;
        int rowg = 16 * t + m;
        #pragma unroll
        for (int j = 0; j < 8; ++j) {
            int k = 8 * quad + j;
            u1.s[j] = bfr(Whh[rowg * 32 + k]);
            float a2v = 0.f;
            if (k == 0) a2v = Wih[rowg * 2];
            else if (k == 1) a2v = Wih[rowg * 2 + 1];
            else if (k == 2) a2v = (rowg < 64) ? (bih[rowg] + bhh[rowg]) : bih[rowg];
            u2.s[j] = bfr(a2v);
        }
        A1[t] = u1.v; A2[t] = u2.v;
    }
    {
        union { short s[8]; short8 v; } u3;
        #pragma unroll
        for (int j = 0; j < 8; ++j) {
            int k = 8 * quad + j;
            float v = (m == 0) ? Wv[k] : (m == 1) ? Wsc[k] : 0.f;
            u3.s[j] = bfr(v);
        }
        A3 = u3.v;
    }
    #pragma unroll
    for (int t = 0; t < 6; ++t) { KEEPA(A1[t]); KEEPA(A2[t]); }
    KEEPA(A3);

    float bn0[4], bn1[4];
    #pragma unroll
    for (int e = 0; e < 4; ++e) {
        int r0 = quad * 4 + e;
        bn0[e] = bhh[64 + r0];  bn1[e] = bhh[80 + r0];
    }
    const float bv0 = bv[0], bs0 = bs[0];

    for (int g0 = blockIdx.x; g0 * GSP < N; g0 += CBLK) {
        const int base0 = g0 * GSP;
        const int s_lo = base0 - (WARM + 1);
        const int s_hi = base0 + GSP;            // includes tN spike
        const int s_lo_c = max(s_lo, 0);
        const int s_hi_c = min(s_hi, N - 1);

        if (lane == 0) tn_sh = T_LEN;
        // entries with nominal spike index < 0 clamp to spike 0 = (t=0, x[0])
        if (s_lo < 0) {
            float x0 = x[0];
            for (int e = lane; e < CHAINS * EPC; e += 64) {
                int n = e / EPC, j = e - n * EPC;
                int s = base0 + n * SEG - (WARM + 1) + j;
                if (s < 0) st[e] = make_float2(0.f, x0);
            }
        }

        // locate chunk range [c0, c1] containing spikes [s_lo_c, s_hi_c]
        int c0 = -1, c1 = -1;
        #pragma unroll
        for (int k = 0; k < 8; ++k) {
            int c = lane * 8 + k;
            if (P[c] <= s_lo_c && s_lo_c < P[c + 1]) c0 = c;
            if (P[c] <= s_hi_c && s_hi_c < P[c + 1]) c1 = c;
        }
        for (int d = 32; d; d >>= 1) {
            c0 = max(c0, __shfl_down(c0, d, 64));
            c1 = max(c1, __shfl_down(c1, d, 64));
        }
        c0 = __shfl(c0, 0, 64);
        c1 = __shfl(c1, 0, 64);

        // decode mask chunks -> stage (t, x_t) into st[]
        for (int c = c0; c <= c1; ++c) {
            const uint8_t* mp = mask + c * 1024 + lane * 16;
            uint4 mw = *(const uint4*)mp;                 // 16 bytes, each 0/1
            int cl = __popc(mw.x) + __popc(mw.y) + __popc(mw.z) + __popc(mw.w);
            int ic = cl;
            for (int d = 1; d < 64; d <<= 1) {
                int u = __shfl_up(ic, d, 64);
                if (lane >= d) ic += u;
            }
            int s = P[c] + ic - cl;                       // global idx of this lane's 1st spike
            unsigned wds[4] = {mw.x, mw.y, mw.z, mw.w};
            #pragma unroll
            for (int wq = 0; wq < 4; ++wq) {
                unsigned W = wds[wq];
                #pragma unroll
                for (int by = 0; by < 4; ++by) {
                    if ((W >> (8 * by)) & 1u) {
                        if (s >= s_lo_c && s <= s_hi_c) {
                            int t = c * 1024 + lane * 16 + wq * 4 + by;
                            int rel = s - base0;          // in [-9, 128]
                            if (rel == GSP) {
                                tn_sh = t;
                            } else {
                                float xv = x[t];
                                int n_lo = rel >> 3;              // ceil((rel-7)/8)
                                int n_hi = (rel + 9) >> 3;        // floor((rel+9)/8)
                                n_lo = max(n_lo, 0); n_hi = min(n_hi, CHAINS - 1);
                                for (int n = n_lo; n <= n_hi; ++n) {
                                    int j = rel + (WARM + 1) - SEG * n;  // in [0,16]
                                    st[n * EPC + j] = make_float2((float)t, xv);
                                }
                            }
                        }
                        ++s;
                    }
                }
            }
        }
        __builtin_amdgcn_wave_barrier();
        const int tN = tn_sh;

        float h0[4], h1[4];
        #pragma unroll
        for (int e = 0; e < 4; ++e) { h0[e] = 0.f; h1[e] = 0.f; }
        short8 B1 = (short8)0;
        float tprev = st[m * EPC].x;

        for (int j = 0; j < SEG + WARM; ++j) {
            float2 cur = st[m * EPC + j + 1];   // 4 lanes/chain same addr: broadcast
            float xt = cur.y;
            float d = (cur.x - tprev) * 0.0078125f;
            tprev = cur.x;

            unsigned p0 = (__float_as_uint(d) & 0xFFFF0000u) | (__float_as_uint(xt) >> 16);
            unsigned p1 = 0x00003F80u;
            p0 = (quad == 0) ? p0 : 0u;
            p1 = (quad == 0) ? p1 : 0u;
            union { unsigned u[4]; short8 v; } b2u;
            b2u.u[0] = p0; b2u.u[1] = p1; b2u.u[2] = 0u; b2u.u[3] = 0u;
            short8 B2 = b2u.v;

            f4 z4 = {0.f, 0.f, 0.f, 0.f};
            f4 Drz[4], Dh0, Dh1, Di0, Di1;
            // input-term MFMAs first (independent of B1 -> off critical path)
            f4 tmp0 = __builtin_amdgcn_mfma_f32_16x16x32_bf16(A2[0], B2, z4, 0, 0, 0);
            f4 tmp1 = __builtin_amdgcn_mfma_f32_16x16x32_bf16(A2[1], B2, z4, 0, 0, 0);
            f4 tmp2 = __builtin_amdgcn_mfma_f32_16x16x32_bf16(A2[2], B2, z4, 0, 0, 0);
            f4 tmp3 = __builtin_amdgcn_mfma_f32_16x16x32_bf16(A2[3], B2, z4, 0, 0, 0);
            Di0 = __builtin_amdgcn_mfma_f32_16x16x32_bf16(A2[4], B2, z4, 0, 0, 0);
            Di1 = __builtin_amdgcn_mfma_f32_16x16x32_bf16(A2[5], B2, z4, 0, 0, 0);
            Drz[0] = __builtin_amdgcn_mfma_f32_16x16x32_bf16(A1[0], B1, tmp0, 0, 0, 0);
            Drz[1] = __builtin_amdgcn_mfma_f32_16x16x32_bf16(A1[1], B1, tmp1, 0, 0, 0);
            Drz[2] = __builtin_amdgcn_mfma_f32_16x16x32_bf16(A1[2], B1, tmp2, 0, 0, 0);
            Drz[3] = __builtin_amdgcn_mfma_f32_16x16x32_bf16(A1[3], B1, tmp3, 0, 0, 0);
            Dh0 = __builtin_amdgcn_mfma_f32_16x16x32_bf16(A1[4], B1, z4, 0, 0, 0);
            Dh1 = __builtin_amdgcn_mfma_f32_16x16x32_bf16(A1[5], B1, z4, 0, 0, 0);

            #pragma unroll
            for (int e = 0; e < 4; ++e) {
                float r0 = __builtin_amdgcn_rcpf(1.f + __builtin_amdgcn_exp2f(-1.44269504089f * Drz[0][e]));
                float r1 = __builtin_amdgcn_rcpf(1.f + __builtin_amdgcn_exp2f(-1.44269504089f * Drz[1][e]));
                float zz0 = __builtin_amdgcn_rcpf(1.f + __builtin_amdgcn_exp2f(-1.44269504089f * Drz[2][e]));
                float zz1 = __builtin_amdgcn_rcpf(1.f + __builtin_amdgcn_exp2f(-1.44269504089f * Drz[3][e]));
                float np0 = fmaf(r0, Dh0[e] + bn0[e], Di0[e]);
                float np1 = fmaf(r1, Dh1[e] + bn1[e], Di1[e]);
                float en0 = __builtin_amdgcn_exp2f(2.88539008178f * np0);
                float en1 = __builtin_amdgcn_exp2f(2.88539008178f * np1);
                float n0 = fmaf(-2.f, __builtin_amdgcn_rcpf(1.f + en0), 1.f);
                float n1 = fmaf(-2.f, __builtin_amdgcn_rcpf(1.f + en1), 1.f);
                h0[e] = fmaf(zz0, h0[e] - n0, n0);
                h1[e] = fmaf(zz1, h1[e] - n1, n1);
            }

            // pack h as bf16 pairs, LDS C->B transpose (stride 20: b128 read)
            unsigned q0 = (__float_as_uint(h0[1]) & 0xFFFF0000u) | (__float_as_uint(h0[0]) >> 16);
            unsigned q1 = (__float_as_uint(h0[3]) & 0xFFFF0000u) | (__float_as_uint(h0[2]) >> 16);
            unsigned q2 = (__float_as_uint(h1[1]) & 0xFFFF0000u) | (__float_as_uint(h1[0]) >> 16);
            unsigned q3 = (__float_as_uint(h1[3]) & 0xFFFF0000u) | (__float_as_uint(h1[2]) >> 16);
            *(uint2*)&hx[m * 20 + 2 * quad]     = make_uint2(q0, q1);
            *(uint2*)&hx[m * 20 + 8 + 2 * quad] = make_uint2(q2, q3);
            __builtin_amdgcn_wave_barrier();
            union { uint4 u; short8 v; } bu;
            bu.u = *(const uint4*)&hx[m * 20 + 4 * quad];
            B1 = bu.v;

            // a,b of this spike via one MFMA (rows 0,1 of A3)
            if (j >= WARM) {
                f4 Dab = __builtin_amdgcn_mfma_f32_16x16x32_bf16(A3, B1, z4, 0, 0, 0);
                if (quad == 0) {
                    int sg = base0 + m * SEG + (j - WARM);
                    if (sg < N)
                        *(float2*)&ab[2 * (m * SEG + j - WARM)] =
                            make_float2(Dab[0] + bv0, Dab[1] + bs0);
                }
            }
        }
        __builtin_amdgcn_wave_barrier();

        // ---- expansion: spike s fills out[t] for t in [t_s, t_next) ----
        #pragma unroll
        for (int h = 0; h < 2; ++h) {
            int sl = lane + 64 * h;               // local spike 0..127
            int sg = base0 + sl;
            if (sg < N) {
                int n = sl >> 3, jj = sl & 7;
                float ts = st[n * EPC + (WARM + 1) + jj].x;
                int tnext;
                if (sg + 1 >= N) tnext = T_LEN;
                else if (sl + 1 < GSP) {
                    int n2 = (sl + 1) >> 3, j2 = (sl + 1) & 7;
                    tnext = (int)st[n2 * EPC + (WARM + 1) + j2].x;
                } else tnext = tN;
                float2 abv = *(const float2*)&ab[2 * sl];
                int tsi = (int)ts;
                for (int t = tsi; t < tnext; ++t)
                    out[t] = fmaf(abv.y, (float)(t - tsi) * 0.0078125f, abv.x);
            }
        }
        __builtin_amdgcn_wave_barrier();
    }
}

extern "C" void kernel_launch(void* const* d_in, const int* in_sizes, int n_in,
                              void* d_out, int out_size, void* d_ws, size_t ws_size,
                              hipStream_t stream)
{
    const float* x   = (const float*)d_in[0];
    const float* Wih = (const float*)d_in[1];
    const float* Whh = (const float*)d_in[2];
    const float* bih = (const float*)d_in[3];
    const float* bhh = (const float*)d_in[4];
    const float* Wv  = (const float*)d_in[5];
    const float* bv  = (const float*)d_in[6];
    const float* Wsc = (const float*)d_in[7];
    const float* bs  = (const float*)d_in[8];
    float* out = (float*)d_out;

    char* ws = (char*)d_ws;
    uint8_t* mask = (uint8_t*)(ws + OFF_MASK);
    int* cnt  = (int*)(ws + OFF_CNT);

    k_mask<<<512, 256, 0, stream>>>(x, mask, out, out_size, cnt);
    k_chain<<<CBLK, 64, 0, stream>>>(Whh, Wih, bih, bhh, mask, cnt, x,
                                     Wv, bv, Wsc, bs, out, out_size);
}

// Round 7
// 102.724 us; speedup vs baseline: 2.2497x; 1.0590x over previous
//
#include <hip/hip_runtime.h>
#include <stdint.h>

#define T_LEN 524288
#define SEG 8
#define WARM 8
#define EPC (SEG + WARM + 1)   // 17 staged (t,x) entries per chain
#define CHAINS 16
#define GSP (CHAINS * SEG)     // 128 spikes per wave-group
#define CBLK 1536              // chain blocks (1 wave each), grid-stride
#define NCH 512                // chunks (1024 t each)

typedef short short8 __attribute__((ext_vector_type(8)));
typedef float f4 __attribute__((ext_vector_type(4)));
#define KEEPA(v) asm volatile("" : "+v"(v))

// ---- workspace layout (bytes) ----
static const size_t OFF_CNT = 0;                       // 512 int
static const size_t OFF_SPK = 8192;                    // NCH*1024 int (chunk-local slots)

__device__ __forceinline__ short bfr(float f) {        // fp32 -> bf16 RNE
    uint32_t u = __float_as_uint(f);
    u = (u + 0x7fffu + ((u >> 16) & 1u)) >> 16;
    return (short)u;
}

// padded LDS index: +1 word per 32 -> lane-stride-4 accesses are 2 lanes/bank (free)
#define IDX(j) ((j) + ((j) >> 5))

// ---- K1: spike mask via block-local prefix of x^2 + block-local spike scatter ----
__global__ __launch_bounds__(256) void k_mask(const float* __restrict__ x,
                                              float* __restrict__ out, int out_size,
                                              int* __restrict__ cnt,
                                              int* __restrict__ spk)
{
    __shared__ float tile[1190];                        // 1154 + pad
    __shared__ float cs2[1190];                         // inclusive prefix of squares
    __shared__ float wsum[4];
    __shared__ int wtot[4];
    const int bs = blockIdx.x * 1024;
    const int tid = threadIdx.x;
    const int lane = tid & 63, w = tid >> 6;
    for (int j = tid; j < 1154; j += 256) {
        int g = bs - 130 + j;
        tile[IDX(j)] = (g >= 0) ? x[g] : 0.f;
    }
    __syncthreads();

    const int j0 = tid * 5;
    float p[5];
    float run = 0.f;
    #pragma unroll
    for (int k = 0; k < 5; ++k) {
        float v = (j0 + k < 1154) ? tile[IDX(j0 + k)] : 0.f;
        run = fmaf(v, v, run);
        p[k] = run;
    }
    float incl = run;
    for (int d = 1; d < 64; d <<= 1) {
        float u = __shfl_up(incl, d, 64);
        if (lane >= d) incl += u;
    }
    if (lane == 63) wsum[w] = incl;
    __syncthreads();
    float base = incl - run;            // exclusive within wave
    for (int i = 0; i < w; ++i) base += wsum[i];
    #pragma unroll
    for (int k = 0; k < 5; ++k)
        if (j0 + k < 1154) cs2[IDX(j0 + k)] = base + p[k];
    __syncthreads();

    const int loc = tid * 4;
    float tv[6];
    #pragma unroll
    for (int q = 0; q < 6; ++q) tv[q] = tile[IDX(loc + 128 + q)];
    float4 mf; int mbit[4]; int msum = 0;
    float* fp = &mf.x;
    #pragma unroll
    for (int it = 0; it < 4; ++it) {
        int t = bs + loc + it;
        int c = t < 128 ? (t < 1 ? 1 : t) : 128;
        float s = cs2[IDX(loc + 129 + it)] - cs2[IDX(loc + 1 + it)];
        float rms = sqrtf(fmaxf(s, 0.f) / (float)c) + 1e-8f;
        float xt = tv[it + 2];
        float pr = 2.f * tv[it + 1] - tv[it];
        bool m = (t < 2) || (fabsf(xt - pr) > 2.5f * rms);
        mbit[it] = m ? 1 : 0; fp[it] = m ? 1.f : 0.f; msum += m ? 1 : 0;
    }
    int oi = T_LEN + 1 + bs + loc;
    if (oi + 3 < out_size) *(float4*)(out + oi) = mf;

    // block-local scatter: rank within block -> spk[b*1024 + rank] = t
    int e1 = mbit[0], e2 = mbit[0] + mbit[1], e3 = e2 + mbit[2];
    int incs = msum;
    for (int d = 1; d < 64; d <<= 1) {
        int u = __shfl_up(incs, d, 64);
        if (lane >= d) incs += u;
    }
    if (lane == 63) wtot[w] = incs;
    __syncthreads();
    int woff = 0;
    for (int i = 0; i < w; ++i) woff += wtot[i];
    int texcl = woff + incs - msum;
    int ee[4] = {0, e1, e2, e3};
    int* sp = spk + blockIdx.x * 1024 + texcl;
    #pragma unroll
    for (int k = 0; k < 4; ++k)
        if (mbit[k]) sp[ee[k]] = bs + loc + k;
    if (tid == 0) cnt[blockIdx.x] = wtot[0] + wtot[1] + wtot[2] + wtot[3];
}

// ---- K2: MFMA-batched GRU chains; spike lookup via P[]-walk + indexed spk load ----
__global__ __attribute__((amdgpu_waves_per_eu(2)))
__launch_bounds__(64)
void k_chain(const float* __restrict__ Whh,
             const float* __restrict__ Wih,
             const float* __restrict__ bih,
             const float* __restrict__ bhh,
             const int* __restrict__ spk,
             const int* __restrict__ cnt,
             const float* __restrict__ x,
             const float* __restrict__ Wv,
             const float* __restrict__ bv,
             const float* __restrict__ Wsc,
             const float* __restrict__ bs,
             float* __restrict__ out, int out_size)
{
    __shared__ float2   st[CHAINS * EPC];   // staged (t, x_t)
    __shared__ unsigned hx[CHAINS * 20];    // packed bf16 h (C->B transpose)
    __shared__ float    ab[2 * GSP];        // (a,b) per spike
    __shared__ int      P[NCH + 1];         // exclusive prefix of chunk counts
    __shared__ int      tn_sh;              // time of spike base0+GSP (or T_LEN)

    const int lane = threadIdx.x;
    const int m = lane & 15;
    const int quad = lane >> 4;

    // ---- prologue: one-wave prefix of the 512 chunk counts (8 values/lane) ----
    int vv[8]; int locs = 0;
    #pragma unroll
    for (int k = 0; k < 8; ++k) { vv[k] = cnt[lane * 8 + k]; locs += vv[k]; }
    int incp = locs;
    for (int d = 1; d < 64; d <<= 1) {
        int u = __shfl_up(incp, d, 64);
        if (lane >= d) incp += u;
    }
    int runp = incp - locs;
    #pragma unroll
    for (int k = 0; k < 8; ++k) { P[lane * 8 + k] = runp; runp += vv[k]; }
    if (lane == 63) P[NCH] = incp;
    __builtin_amdgcn_wave_barrier();
    const int N = P[NCH];
    if (blockIdx.x == 0 && lane == 0 && T_LEN < out_size) out[T_LEN] = (float)N;

    // ---- A fragments (static): A[m][k], k = 8*quad + j ----
    short8 A1[6], A2[6], A3;
    #pragma unroll
    for (int t = 0; t < 6; ++t) {
        union { short s[8]; short8 v; } u1, u2;
        int rowg = 16 * t + m;
        #pragma unroll
        for (int j = 0; j < 8; ++j) {
            int k = 8 * quad + j;
            u1.s[j] = bfr(Whh[rowg * 32 + k]);
            float a2v = 0.f;
            if (k == 0) a2v = Wih[rowg * 2];
            else if (k == 1) a2v = Wih[rowg * 2 + 1];
            else if (k == 2) a2v = (rowg < 64) ? (bih[rowg] + bhh[rowg]) : bih[rowg];
            u2.s[j] = bfr(a2v);
        }
        A1[t] = u1.v; A2[t] = u2.v;
    }
    {
        union { short s[8]; short8 v; } u3;
        #pragma unroll
        for (int j = 0; j < 8; ++j) {
            int k = 8 * quad + j;
            float v = (m == 0) ? Wv[k] : (m == 1) ? Wsc[k] : 0.f;
            u3.s[j] = bfr(v);
        }
        A3 = u3.v;
    }
    #pragma unroll
    for (int t = 0; t < 6; ++t) { KEEPA(A1[t]); KEEPA(A2[t]); }
    KEEPA(A3);

    float bn0[4], bn1[4];
    #pragma unroll
    for (int e = 0; e < 4; ++e) {
        int r0 = quad * 4 + e;
        bn0[e] = bhh[64 + r0];  bn1[e] = bhh[80 + r0];
    }
    const float bv0 = bv[0], bs0 = bs[0];

    for (int g0 = blockIdx.x; g0 * GSP < N; g0 += CBLK) {
        const int base0 = g0 * GSP;
        const int s_lo_c = max(base0 - (WARM + 1), 0);

        // start chunk: the c with P[c] <= s_lo_c < P[c+1] (lane-parallel probe)
        int c0 = -1;
        #pragma unroll
        for (int k = 0; k < 8; ++k) {
            int c = lane * 8 + k;
            if (P[c] <= s_lo_c && s_lo_c < P[c + 1]) c0 = c;
        }
        for (int d = 32; d; d >>= 1) c0 = max(c0, __shfl_down(c0, d, 64));
        const int c0w = __shfl(c0, 0, 64);

        // stage (t, x_t): entry j of chain n = spike base0 + n*SEG - 9 + j (clamped)
        for (int e = lane; e < CHAINS * EPC; e += 64) {
            int n = e / EPC, j = e - n * EPC;
            int s = base0 + n * SEG - (WARM + 1) + j;
            s = min(max(s, 0), N - 1);
            int c = c0w;
            while (P[c + 1] <= s) ++c;          // <= ~3 steps typical
            int t = spk[c * 1024 + (s - P[c])];
            st[e] = make_float2((float)t, x[t]);
        }
        if (lane == 0) {
            int nid = base0 + GSP;
            if (nid >= N) tn_sh = T_LEN;
            else {
                int c = c0w;
                while (P[c + 1] <= nid) ++c;
                tn_sh = spk[c * 1024 + (nid - P[c])];
            }
        }
        __builtin_amdgcn_wave_barrier();
        const int tN = tn_sh;

        float h0[4], h1[4];
        #pragma unroll
        for (int e = 0; e < 4; ++e) { h0[e] = 0.f; h1[e] = 0.f; }
        short8 B1 = (short8)0;
        float tprev = st[m * EPC].x;

        for (int j = 0; j < SEG + WARM; ++j) {
            float2 cur = st[m * EPC + j + 1];   // 4 lanes/chain same addr: broadcast
            float xt = cur.y;
            float d = (cur.x - tprev) * 0.0078125f;
            tprev = cur.x;

            unsigned p0 = (__float_as_uint(d) & 0xFFFF0000u) | (__float_as_uint(xt) >> 16);
            unsigned p1 = 0x00003F80u;
            p0 = (quad == 0) ? p0 : 0u;
            p1 = (quad == 0) ? p1 : 0u;
            union { unsigned u[4]; short8 v; } b2u;
            b2u.u[0] = p0; b2u.u[1] = p1; b2u.u[2] = 0u; b2u.u[3] = 0u;
            short8 B2 = b2u.v;

            f4 z4 = {0.f, 0.f, 0.f, 0.f};
            f4 Drz[4], Dh0, Dh1, Di0, Di1;
            // input-term MFMAs first (independent of B1 -> off critical path)
            f4 tmp0 = __builtin_amdgcn_mfma_f32_16x16x32_bf16(A2[0], B2, z4, 0, 0, 0);
            f4 tmp1 = __builtin_amdgcn_mfma_f32_16x16x32_bf16(A2[1], B2, z4, 0, 0, 0);
            f4 tmp2 = __builtin_amdgcn_mfma_f32_16x16x32_bf16(A2[2], B2, z4, 0, 0, 0);
            f4 tmp3 = __builtin_amdgcn_mfma_f32_16x16x32_bf16(A2[3], B2, z4, 0, 0, 0);
            Di0 = __builtin_amdgcn_mfma_f32_16x16x32_bf16(A2[4], B2, z4, 0, 0, 0);
            Di1 = __builtin_amdgcn_mfma_f32_16x16x32_bf16(A2[5], B2, z4, 0, 0, 0);
            Drz[0] = __builtin_amdgcn_mfma_f32_16x16x32_bf16(A1[0], B1, tmp0, 0, 0, 0);
            Drz[1] = __builtin_amdgcn_mfma_f32_16x16x32_bf16(A1[1], B1, tmp1, 0, 0, 0);
            Drz[2] = __builtin_amdgcn_mfma_f32_16x16x32_bf16(A1[2], B1, tmp2, 0, 0, 0);
            Drz[3] = __builtin_amdgcn_mfma_f32_16x16x32_bf16(A1[3], B1, tmp3, 0, 0, 0);
            Dh0 = __builtin_amdgcn_mfma_f32_16x16x32_bf16(A1[4], B1, z4, 0, 0, 0);
            Dh1 = __builtin_amdgcn_mfma_f32_16x16x32_bf16(A1[5], B1, z4, 0, 0, 0);

            #pragma unroll
            for (int e = 0; e < 4; ++e) {
                float r0 = __builtin_amdgcn_rcpf(1.f + __builtin_amdgcn_exp2f(-1.44269504089f * Drz[0][e]));
                float r1 = __builtin_amdgcn_rcpf(1.f + __builtin_amdgcn_exp2f(-1.44269504089f * Drz[1][e]));
                float zz0 = __builtin_amdgcn_rcpf(1.f + __builtin_amdgcn_exp2f(-1.44269504089f * Drz[2][e]));
                float zz1 = __builtin_amdgcn_rcpf(1.f + __builtin_amdgcn_exp2f(-1.44269504089f * Drz[3][e]));
                float np0 = fmaf(r0, Dh0[e] + bn0[e], Di0[e]);
                float np1 = fmaf(r1, Dh1[e] + bn1[e], Di1[e]);
                float en0 = __builtin_amdgcn_exp2f(2.88539008178f * np0);
                float en1 = __builtin_amdgcn_exp2f(2.88539008178f * np1);
                float n0 = fmaf(-2.f, __builtin_amdgcn_rcpf(1.f + en0), 1.f);
                float n1 = fmaf(-2.f, __builtin_amdgcn_rcpf(1.f + en1), 1.f);
                h0[e] = fmaf(zz0, h0[e] - n0, n0);
                h1[e] = fmaf(zz1, h1[e] - n1, n1);
            }

            // pack h as bf16 pairs, LDS C->B transpose (stride 20: b128 read)
            unsigned q0 = (__float_as_uint(h0[1]) & 0xFFFF0000u) | (__float_as_uint(h0[0]) >> 16);
            unsigned q1 = (__float_as_uint(h0[3]) & 0xFFFF0000u) | (__float_as_uint(h0[2]) >> 16);
            unsigned q2 = (__float_as_uint(h1[1]) & 0xFFFF0000u) | (__float_as_uint(h1[0]) >> 16);
            unsigned q3 = (__float_as_uint(h1[3]) & 0xFFFF0000u) | (__float_as_uint(h1[2]) >> 16);
            *(uint2*)&hx[m * 20 + 2 * quad]     = make_uint2(q0, q1);
            *(uint2*)&hx[m * 20 + 8 + 2 * quad] = make_uint2(q2, q3);
            __builtin_amdgcn_wave_barrier();
            union { uint4 u; short8 v; } bu;
            bu.u = *(const uint4*)&hx[m * 20 + 4 * quad];
            B1 = bu.v;

            // a,b of this spike via one MFMA (rows 0,1 of A3)
            if (j >= WARM) {
                f4 Dab = __builtin_amdgcn_mfma_f32_16x16x32_bf16(A3, B1, z4, 0, 0, 0);
                if (quad == 0) {
                    int sg = base0 + m * SEG + (j - WARM);
                    if (sg < N)
                        *(float2*)&ab[2 * (m * SEG + j - WARM)] =
                            make_float2(Dab[0] + bv0, Dab[1] + bs0);
                }
            }
        }
        __builtin_amdgcn_wave_barrier();

        // ---- expansion: spike s fills out[t] for t in [t_s, t_next) ----
        #pragma unroll
        for (int h = 0; h < 2; ++h) {
            int sl = lane + 64 * h;               // local spike 0..127
            int sg = base0 + sl;
            if (sg < N) {
                int n = sl >> 3, jj = sl & 7;
                float ts = st[n * EPC + (WARM + 1) + jj].x;
                int tnext;
                if (sg + 1 >= N) tnext = T_LEN;
                else if (sl + 1 < GSP) {
                    int n2 = (sl + 1) >> 3, j2 = (sl + 1) & 7;
                    tnext = (int)st[n2 * EPC + (WARM + 1) + j2].x;
                } else tnext = tN;
                float2 abv = *(const float2*)&ab[2 * sl];
                int tsi = (int)ts;
                for (int t = tsi; t < tnext; ++t)
                    out[t] = fmaf(abv.y, (float)(t - tsi) * 0.0078125f, abv.x);
            }
        }
        __builtin_amdgcn_wave_barrier();
    }
}

extern "C" void kernel_launch(void* const* d_in, const int* in_sizes, int n_in,
                              void* d_out, int out_size, void* d_ws, size_t ws_size,
                              hipStream_t stream)
{
    const float* x   = (const float*)d_in[0];
    const float* Wih = (const float*)d_in[1];
    const float* Whh = (const float*)d_in[2];
    const float* bih = (const float*)d_in[3];
    const float* bhh = (const float*)d_in[4];
    const float* Wv  = (const float*)d_in[5];
    const float* bv  = (const float*)d_in[6];
    const float* Wsc = (const float*)d_in[7];
    const float* bs  = (const float*)d_in[8];
    float* out = (float*)d_out;

    char* ws = (char*)d_ws;
    int* cnt = (int*)(ws + OFF_CNT);
    int* spk = (int*)(ws + OFF_SPK);

    k_mask<<<512, 256, 0, stream>>>(x, out, out_size, cnt, spk);
    k_chain<<<CBLK, 64, 0, stream>>>(Whh, Wih, bih, bhh, spk, cnt, x,
                                     Wv, bv, Wsc, bs, out, out_size);
}